// Round 3
// baseline (276.122 us; speedup 1.0000x reference)
//
#include <hip/hip_runtime.h>

// Shapes (fixed): B=64 H=16 T=4 Dk=128 Dv=256
#define BH    1024
#define TT    4
#define DK    128
#define DV    256
#define KSEG  16       // k-groups (lanes) cooperating on one v-tile
#define KLEN  8        // k rows per thread = DK/KSEG
#define QV    64       // v-columns per block (4 blocks per bh)
#define LDP   9        // padded LDS row stride (8+1; kg*9 mod 32 all distinct)

// Native clang vector type for nontemporal builtins (HIP float4 is a struct
// and is rejected by __builtin_nontemporal_store).
typedef float vfloat4 __attribute__((ext_vector_type(4)));

// R3 = R2 with the nontemporal-store type fixed. Block = 256 threads =
// 16 vg x 16 kg. Thread (vg,kg) owns state tile [8*kg .. 8*kg+7] x
// [4*vg .. 4*vg+3] as float4 s4[8] (32 VGPRs). 4096 blocks (4 col-quarters
// per bh) -> >=2 resident generations per CU, so block starts stagger and
// read/write streams interleave instead of phase-aligned bursts (R1
// post-mortem: waves averaged 22us lifetime, machine idle ~75%).
// g/beta/v are all prefetched before the T-loop (no per-t exposed latency).
// State-out and out use nontemporal stores: 132 MB of write traffic skips
// L2/L3, preserving L3 residency of state-in (FETCH already shows L3
// absorbing ~half the reads).
__global__ __launch_bounds__(256)
void delta_rule_kernel(const float* __restrict__ q,
                       const float* __restrict__ k,
                       const float* __restrict__ v,
                       const float* __restrict__ g,
                       const float* __restrict__ beta,
                       const float* __restrict__ s0,
                       float* __restrict__ out)
{
    const int bh      = blockIdx.x >> 2;
    const int quarter = blockIdx.x & 3;
    const int tid  = threadIdx.x;
    const int kg   = tid & (KSEG - 1);            // 0..15 (in-wave, adjacent lanes)
    const int vg   = tid >> 4;                    // 0..15
    const int vcol = quarter * QV + vg * 4;       // first of this thread's 4 v-cols
    const int kr0  = kg * KLEN;                   // first of this thread's 8 k-rows

    const float* __restrict__ sin_p = s0 + (size_t)bh * DK * DV;
    float* __restrict__ out_p  = out + (size_t)bh * TT * DV;
    float* __restrict__ sout_p = out + (size_t)BH * TT * DV + (size_t)bh * DK * DV;

    const float* __restrict__ kbase = k    + (size_t)bh * TT * DK;
    const float* __restrict__ qbase = q    + (size_t)bh * TT * DK;
    const float* __restrict__ vbase = v    + (size_t)bh * TT * DV;
    const float* __restrict__ gbase = g    + (size_t)bh * TT;
    const float* __restrict__ bbase = beta + (size_t)bh * TT;

    // All-t staging buffers: [t][kg*LDP + kk].
    __shared__ float ks[TT][KSEG * LDP];
    __shared__ float qs[TT][KSEG * LDP];

    // --- staging loads FIRST (oldest in vmcnt queue -> retire first) ---
    // TT*DK = 512 floats each for k and q; 256 threads -> 2 elements each.
    const int i0 = tid;
    const int i1 = tid + 256;
    const float kl0 = kbase[i0];
    const float kl1 = kbase[i1];
    const float ql0 = qbase[i0];
    const float ql1 = qbase[i1];

    // --- per-block uniforms + v rows for ALL t, prefetched up front ---
    const float4 gq = *(const float4*)&gbase[0];   // g[t], t=0..3 (16B-aligned)
    const float4 bq = *(const float4*)&bbase[0];   // beta[t]
    float4 v4a[TT];
#pragma unroll
    for (int t = 0; t < TT; ++t)
        v4a[t] = *(const float4*)&vbase[t * DV + vcol];

    // --- state tile loads: 8 x dwordx4; 16 rows x 64B segments per instr ---
    float4 s4[KLEN];
#pragma unroll
    for (int kk = 0; kk < KLEN; ++kk)
        s4[kk] = *(const float4*)&sin_p[(size_t)(kr0 + kk) * DV + vcol];

    // --- LDS write (waits only on the 4 staging loads), single barrier ---
    {
        const int t0 = i0 >> 7, j0 = i0 & 127;   // j = k-row index
        const int t1 = i1 >> 7, j1 = i1 & 127;
        ks[t0][(j0 >> 3) * LDP + (j0 & 7)] = kl0;
        ks[t1][(j1 >> 3) * LDP + (j1 & 7)] = kl1;
        qs[t0][(j0 >> 3) * LDP + (j0 & 7)] = ql0;
        qs[t1][(j1 >> 3) * LDP + (j1 & 7)] = ql1;
    }
    __syncthreads();   // the ONLY barrier in the kernel

    const float garr[TT] = {gq.x, gq.y, gq.z, gq.w};
    const float barr[TT] = {bq.x, bq.y, bq.z, bq.w};

#pragma unroll
    for (int t = 0; t < TT; ++t) {
        const float gt = expf(garr[t]);
        const float bt = barr[t];
        const float4 v4 = v4a[t];

        // decay + key readout partial (8-deep, 4 independent chains)
        float4 kv = make_float4(0.f, 0.f, 0.f, 0.f);
#pragma unroll
        for (int kk = 0; kk < KLEN; ++kk) {
            const float kt = ks[t][kg * LDP + kk];
            s4[kk].x *= gt; s4[kk].y *= gt; s4[kk].z *= gt; s4[kk].w *= gt;
            kv.x = fmaf(s4[kk].x, kt, kv.x);
            kv.y = fmaf(s4[kk].y, kt, kv.y);
            kv.z = fmaf(s4[kk].z, kt, kv.z);
            kv.w = fmaf(s4[kk].w, kt, kv.w);
        }
        // butterfly over the 16 kg lanes -> all lanes hold the full k-sum
#pragma unroll
        for (int m = 1; m < KSEG; m <<= 1) {
            kv.x += __shfl_xor(kv.x, m);
            kv.y += __shfl_xor(kv.y, m);
            kv.z += __shfl_xor(kv.z, m);
            kv.w += __shfl_xor(kv.w, m);
        }

        float4 d4;
        d4.x = (v4.x - kv.x) * bt;
        d4.y = (v4.y - kv.y) * bt;
        d4.z = (v4.z - kv.z) * bt;
        d4.w = (v4.w - kv.w) * bt;

        // rank-1 update + query readout partial
        float4 o4 = make_float4(0.f, 0.f, 0.f, 0.f);
#pragma unroll
        for (int kk = 0; kk < KLEN; ++kk) {
            const float kt = ks[t][kg * LDP + kk];
            const float qt = qs[t][kg * LDP + kk];
            s4[kk].x = fmaf(kt, d4.x, s4[kk].x);
            s4[kk].y = fmaf(kt, d4.y, s4[kk].y);
            s4[kk].z = fmaf(kt, d4.z, s4[kk].z);
            s4[kk].w = fmaf(kt, d4.w, s4[kk].w);
            o4.x = fmaf(s4[kk].x, qt, o4.x);
            o4.y = fmaf(s4[kk].y, qt, o4.y);
            o4.z = fmaf(s4[kk].z, qt, o4.z);
            o4.w = fmaf(s4[kk].w, qt, o4.w);
        }
#pragma unroll
        for (int m = 1; m < KSEG; m <<= 1) {
            o4.x += __shfl_xor(o4.x, m);
            o4.y += __shfl_xor(o4.y, m);
            o4.z += __shfl_xor(o4.z, m);
            o4.w += __shfl_xor(o4.w, m);
        }
        if (kg == 0) {
            vfloat4 ov = { o4.x, o4.y, o4.z, o4.w };
            __builtin_nontemporal_store(ov, (vfloat4*)&out_p[t * DV + vcol]);
        }
    }

    // Store final state tile: 8 x dwordx4, nontemporal (dead-on-arrival for
    // caches; don't evict the L3-resident state input).
#pragma unroll
    for (int kk = 0; kk < KLEN; ++kk) {
        vfloat4 sv = { s4[kk].x, s4[kk].y, s4[kk].z, s4[kk].w };
        __builtin_nontemporal_store(sv,
            (vfloat4*)&sout_p[(size_t)(kr0 + kk) * DV + vcol]);
    }
}

extern "C" void kernel_launch(void* const* d_in, const int* in_sizes, int n_in,
                              void* d_out, int out_size, void* d_ws, size_t ws_size,
                              hipStream_t stream) {
    const float* q    = (const float*)d_in[0];
    const float* k    = (const float*)d_in[1];
    const float* v    = (const float*)d_in[2];
    const float* g    = (const float*)d_in[3];
    const float* beta = (const float*)d_in[4];
    const float* s0   = (const float*)d_in[5];
    float* out = (float*)d_out;

    delta_rule_kernel<<<dim3(BH * 4), dim3(256), 0, stream>>>(q, k, v, g, beta, s0, out);
}

// Round 4
// 252.866 us; speedup vs baseline: 1.0920x; 1.0920x over previous
//
#include <hip/hip_runtime.h>

// Shapes (fixed): B=64 H=16 T=4 Dk=128 Dv=256
#define BH    1024
#define TT    4
#define DK    128
#define DV    256
#define NW    4          // waves per block
#define RPW   32         // rows per wave = DK/NW

// R4: full-row-contiguous state streaming.
// Theory: R0/R1/R3 all plateau at ~2.35 TB/s (29% peak) regardless of
// occupancy/barriers because every state vmem instruction touched 8-16
// small segments at 1KB stride (the state row pitch) -> channel-interleave
// imbalance. This version: 1024 blocks (one per bh), 4 waves; wave w owns
// rows [32w,32w+32), lane l owns cols [4l,4l+4). Each state load/store
// instruction covers 64 lanes x 16B = one FULL contiguous 1KB row; each
// wave streams a contiguous 32KB run. k-reduction now crosses waves via a
// small LDS partial exchange (1KB/wave/t) + 1 barrier per t.
// Nontemporal stores reverted (R3: +27% write amplification).
__global__ __launch_bounds__(256)
void delta_rule_kernel(const float* __restrict__ q,
                       const float* __restrict__ k,
                       const float* __restrict__ v,
                       const float* __restrict__ g,
                       const float* __restrict__ beta,
                       const float* __restrict__ s0,
                       float* __restrict__ out)
{
    const int bh  = blockIdx.x;
    const int tid = threadIdx.x;
    const int w   = tid >> 6;         // wave 0..3, owns rows [32w, 32w+32)
    const int l   = tid & 63;         // lane, owns cols [4l, 4l+4)
    const int col = l << 2;
    const int r0  = w * RPW;

    const float* __restrict__ sin_p = s0 + (size_t)bh * DK * DV;
    float* __restrict__ out_p  = out + (size_t)bh * TT * DV;
    float* __restrict__ sout_p = out + (size_t)BH * TT * DV + (size_t)bh * DK * DV;

    const float* __restrict__ kbase = k    + (size_t)bh * TT * DK;
    const float* __restrict__ qbase = q    + (size_t)bh * TT * DK;
    const float* __restrict__ vbase = v    + (size_t)bh * TT * DV;
    const float* __restrict__ gbase = g    + (size_t)bh * TT;
    const float* __restrict__ bbase = beta + (size_t)bh * TT;

    __shared__ float ks[TT][DK];             // k, all t (broadcast reads)
    __shared__ float qs[TT][DK];             // q, all t
    __shared__ float kvbuf[TT][NW][DV];      // per-wave kv partials
    __shared__ float obuf [TT][NW][DV];      // per-wave o partials

    // --- staging loads first (oldest in vmcnt queue -> retire first) ---
    const float kl0 = kbase[tid];
    const float kl1 = kbase[tid + 256];
    const float ql0 = qbase[tid];
    const float ql1 = qbase[tid + 256];

    // --- uniforms + v rows for all t ---
    const float4 gq = *(const float4*)&gbase[0];
    const float4 bq = *(const float4*)&bbase[0];
    float4 v4a[TT];
#pragma unroll
    for (int t = 0; t < TT; ++t)
        v4a[t] = *(const float4*)&vbase[t * DV + col];

    // --- state: 32 loads, each one full contiguous 1KB row per wave ---
    float4 s4[RPW];
#pragma unroll
    for (int i = 0; i < RPW; ++i)
        s4[i] = *(const float4*)&sin_p[(size_t)(r0 + i) * DV + col];

    // --- LDS staging (waits only on the 4 k/q loads) ---
    ks[tid >> 7][tid & 127] = kl0;
    qs[tid >> 7][tid & 127] = ql0;
    {
        const int j = tid + 256;
        ks[j >> 7][j & 127] = kl1;
        qs[j >> 7][j & 127] = ql1;
    }
    __syncthreads();

    const float garr[TT] = {gq.x, gq.y, gq.z, gq.w};
    const float barr[TT] = {bq.x, bq.y, bq.z, bq.w};

#pragma unroll
    for (int t = 0; t < TT; ++t) {
        const float gt = expf(garr[t]);
        const float bt = barr[t];

        // decay + per-wave kv partial over this wave's 32 rows
        float4 kv = make_float4(0.f, 0.f, 0.f, 0.f);
#pragma unroll
        for (int j = 0; j < RPW / 4; ++j) {
            const float4 k4 = *(const float4*)&ks[t][r0 + 4 * j]; // broadcast
            const float ka[4] = {k4.x, k4.y, k4.z, k4.w};
#pragma unroll
            for (int rr = 0; rr < 4; ++rr) {
                float4& s = s4[4 * j + rr];
                const float kr = ka[rr];
                s.x *= gt; s.y *= gt; s.z *= gt; s.w *= gt;
                kv.x = fmaf(s.x, kr, kv.x);
                kv.y = fmaf(s.y, kr, kv.y);
                kv.z = fmaf(s.z, kr, kv.z);
                kv.w = fmaf(s.w, kr, kv.w);
            }
        }
        *(float4*)&kvbuf[t][w][col] = kv;
        __syncthreads();   // kv partials of slot t visible

        // every lane sums the 4 wave-partials for its cols (redundant, free)
        const float4 p0 = *(const float4*)&kvbuf[t][0][col];
        const float4 p1 = *(const float4*)&kvbuf[t][1][col];
        const float4 p2 = *(const float4*)&kvbuf[t][2][col];
        const float4 p3 = *(const float4*)&kvbuf[t][3][col];
        float4 d;
        d.x = (v4a[t].x - (p0.x + p1.x + p2.x + p3.x)) * bt;
        d.y = (v4a[t].y - (p0.y + p1.y + p2.y + p3.y)) * bt;
        d.z = (v4a[t].z - (p0.z + p1.z + p2.z + p3.z)) * bt;
        d.w = (v4a[t].w - (p0.w + p1.w + p2.w + p3.w)) * bt;

        // rank-1 update + per-wave o partial
        float4 o = make_float4(0.f, 0.f, 0.f, 0.f);
#pragma unroll
        for (int j = 0; j < RPW / 4; ++j) {
            const float4 k4 = *(const float4*)&ks[t][r0 + 4 * j]; // broadcast
            const float4 q4 = *(const float4*)&qs[t][r0 + 4 * j]; // broadcast
            const float ka[4] = {k4.x, k4.y, k4.z, k4.w};
            const float qa[4] = {q4.x, q4.y, q4.z, q4.w};
#pragma unroll
            for (int rr = 0; rr < 4; ++rr) {
                float4& s = s4[4 * j + rr];
                const float kr = ka[rr];
                const float qr = qa[rr];
                s.x = fmaf(kr, d.x, s.x);
                s.y = fmaf(kr, d.y, s.y);
                s.z = fmaf(kr, d.z, s.z);
                s.w = fmaf(kr, d.w, s.w);
                o.x = fmaf(s.x, qr, o.x);
                o.y = fmaf(s.y, qr, o.y);
                o.z = fmaf(s.z, qr, o.z);
                o.w = fmaf(s.w, qr, o.w);
            }
        }
        *(float4*)&obuf[t][w][col] = o;   // read only after the final barrier
    }

    // --- state out: 32 stores, each one full contiguous 1KB row per wave ---
#pragma unroll
    for (int i = 0; i < RPW; ++i)
        *(float4*)&sout_p[(size_t)(r0 + i) * DV + col] = s4[i];

    __syncthreads();   // all obuf writes visible

    // wave w reduces and stores out row t=w (one contiguous 1KB row)
    {
        const float4 a0 = *(const float4*)&obuf[w][0][col];
        const float4 a1 = *(const float4*)&obuf[w][1][col];
        const float4 a2 = *(const float4*)&obuf[w][2][col];
        const float4 a3 = *(const float4*)&obuf[w][3][col];
        float4 oo;
        oo.x = a0.x + a1.x + a2.x + a3.x;
        oo.y = a0.y + a1.y + a2.y + a3.y;
        oo.z = a0.z + a1.z + a2.z + a3.z;
        oo.w = a0.w + a1.w + a2.w + a3.w;
        *(float4*)&out_p[w * DV + col] = oo;
    }
}

extern "C" void kernel_launch(void* const* d_in, const int* in_sizes, int n_in,
                              void* d_out, int out_size, void* d_ws, size_t ws_size,
                              hipStream_t stream) {
    const float* q    = (const float*)d_in[0];
    const float* k    = (const float*)d_in[1];
    const float* v    = (const float*)d_in[2];
    const float* g    = (const float*)d_in[3];
    const float* beta = (const float*)d_in[4];
    const float* s0   = (const float*)d_in[5];
    float* out = (float*)d_out;

    delta_rule_kernel<<<dim3(BH), dim3(256), 0, stream>>>(q, k, v, g, beta, s0, out);
}

// Round 6
// 248.645 us; speedup vs baseline: 1.1105x; 1.0170x over previous
//
#include <hip/hip_runtime.h>

// Shapes (fixed): B=64 H=16 T=4 Dk=128 Dv=256
#define BH 1024
#define TT 4
#define DK 128
#define DV 256
#define NW 4          // waves per block
#define RPW 32        // rows per wave = DK/NW
#define CH 128        // cols per block (2 blocks per bh)

// R6 = R5 resubmitted (R5 failed on infra, kernel never ran).
// Closed-form unroll of the 4-step delta-rule recurrence:
//   c_t = S0^T k_t, p_t = S0^T q_t, A[s][t]=k_s.k_t, B[s][t]=k_s.q_t
//   d_t = beta_t (v_t - G[t] c_t - sum_{s<t} M[s][t] A[s][t] d_s)
//   o_t = G[t] p_t + sum_{s<=t} M[s][t] B[s][t] d_s
//   S4  = G[3] S0 + sum_t M[t][3] k_t (x) d_t
// where G[t] = prod_{u<=t} e^{g_u}, M[s][t] = prod_{s<u<=t} e^{g_u}.
// This collapses 4 serialized {dot, cross-wave reduce, update} rounds into
// ONE dot pass + ONE reduction + ONE fused update+store pass, so the store
// stream starts immediately after a single reduce and different blocks
// de-phase. 2048 blocks (bh x col-half), 4 waves, float2 state cols/lane
// (64 VGPR state), 12KB LDS -> ~2 resident generations: gen-2 reads overlap
// gen-1 writes (the read/write mixing all previous rounds lacked).
__global__ __launch_bounds__(256)
void delta_rule_kernel(const float* __restrict__ q,
                       const float* __restrict__ k,
                       const float* __restrict__ v,
                       const float* __restrict__ g,
                       const float* __restrict__ beta,
                       const float* __restrict__ s0,
                       float* __restrict__ out)
{
    const int bh   = blockIdx.x >> 1;
    const int half = blockIdx.x & 1;
    const int tid  = threadIdx.x;
    const int w    = tid >> 6;            // wave 0..3, rows [32w, 32w+32)
    const int l    = tid & 63;            // lane, 2 cols
    const int col  = half * CH + (l << 1);
    const int lc   = l << 1;              // col within the half
    const int r0   = w * RPW;

    const float* __restrict__ sin_p = s0 + (size_t)bh * DK * DV;
    float* __restrict__ out_p  = out + (size_t)bh * TT * DV;
    float* __restrict__ sout_p = out + (size_t)BH * TT * DV + (size_t)bh * DK * DV;

    const float* __restrict__ kbase = k    + (size_t)bh * TT * DK;
    const float* __restrict__ qbase = q    + (size_t)bh * TT * DK;
    const float* __restrict__ vbase = v    + (size_t)bh * TT * DV;
    const float* __restrict__ gbase = g    + (size_t)bh * TT;
    const float* __restrict__ bbase = beta + (size_t)bh * TT;

    __shared__ __align__(16) float ksh[DK][4];      // [row][t]
    __shared__ __align__(16) float qsh[DK][4];      // [row][t]
    __shared__ __align__(16) float red[TT][NW][CH]; // partial-sum exchange

    // --- staging loads first (retire first in vmcnt order) ---
    const int e0 = tid, e1 = tid + 256;   // element = t*128 + row
    const float kl0 = kbase[e0], kl1 = kbase[e1];
    const float ql0 = qbase[e0], ql1 = qbase[e1];

    const float4 gq = *(const float4*)&gbase[0];
    const float4 bq = *(const float4*)&bbase[0];
    float2 va[TT];
#pragma unroll
    for (int t = 0; t < TT; ++t)
        va[t] = *(const float2*)&vbase[t * DV + col];

    // --- state tile: 32 x dwordx2, 512B contiguous per wave-instruction ---
    float2 s2[RPW];
#pragma unroll
    for (int i = 0; i < RPW; ++i)
        s2[i] = *(const float2*)&sin_p[(size_t)(r0 + i) * DV + col];

    // --- stage k/q as [row][t] so one b128 read gives all 4 t ---
    ksh[e0 & 127][e0 >> 7] = kl0;
    ksh[e1 & 127][e1 >> 7] = kl1;
    qsh[e0 & 127][e0 >> 7] = ql0;
    qsh[e1 & 127][e1 >> 7] = ql1;
    __syncthreads();                      // barrier 1

    // --- decay products ---
    const float y0 = expf(gq.x), y1 = expf(gq.y), y2 = expf(gq.z), y3 = expf(gq.w);
    const float G0 = y0, G1 = y0*y1, G2 = y0*y1*y2, G3 = y0*y1*y2*y3;
    const float M01 = y1, M02 = y1*y2, M03 = y1*y2*y3;
    const float M12 = y2, M13 = y2*y3;
    const float M23 = y3;
    const float E = G3;
    const float bt0 = bq.x, bt1 = bq.y, bt2 = bq.z, bt3 = bq.w;

    // --- Gram scalars via lane-parallel dot + butterfly (wave-redundant) ---
    const float4 kA = *(const float4*)&ksh[l][0];
    const float4 kB = *(const float4*)&ksh[l + 64][0];
    const float4 qA = *(const float4*)&qsh[l][0];
    const float4 qB = *(const float4*)&qsh[l + 64][0];
    const float a0[4] = {kA.x, kA.y, kA.z, kA.w};
    const float a1[4] = {kB.x, kB.y, kB.z, kB.w};
    const float b0[4] = {qA.x, qA.y, qA.z, qA.w};
    const float b1[4] = {qB.x, qB.y, qB.z, qB.w};
    float AA[4][4];   // k_s . k_t  (s<t used)
    float BB[4][4];   // k_s . q_t  (s<=t used)
#pragma unroll
    for (int s = 0; s < 4; ++s) {
#pragma unroll
        for (int t = 0; t < 4; ++t) {
            if (t > s) {
                float x = fmaf(a1[s], a1[t], a0[s] * a0[t]);
#pragma unroll
                for (int m = 1; m < 64; m <<= 1) x += __shfl_xor(x, m);
                AA[s][t] = x;
            }
            if (t >= s) {
                float x = fmaf(a1[s], b1[t], a0[s] * b0[t]);
#pragma unroll
                for (int m = 1; m < 64; m <<= 1) x += __shfl_xor(x, m);
                BB[s][t] = x;
            }
        }
    }

    // --- pass 1: c_t = S0^T k_t partials over this wave's 32 rows ---
    float2 c[TT] = {{0.f,0.f},{0.f,0.f},{0.f,0.f},{0.f,0.f}};
#pragma unroll
    for (int i = 0; i < RPW; ++i) {
        const float4 k4 = *(const float4*)&ksh[r0 + i][0];  // broadcast
        c[0].x = fmaf(s2[i].x, k4.x, c[0].x); c[0].y = fmaf(s2[i].y, k4.x, c[0].y);
        c[1].x = fmaf(s2[i].x, k4.y, c[1].x); c[1].y = fmaf(s2[i].y, k4.y, c[1].y);
        c[2].x = fmaf(s2[i].x, k4.z, c[2].x); c[2].y = fmaf(s2[i].y, k4.z, c[2].y);
        c[3].x = fmaf(s2[i].x, k4.w, c[3].x); c[3].y = fmaf(s2[i].y, k4.w, c[3].y);
    }
#pragma unroll
    for (int t = 0; t < TT; ++t)
        *(float2*)&red[t][w][lc] = c[t];
    __syncthreads();                      // barrier 2: c partials visible
#pragma unroll
    for (int t = 0; t < TT; ++t) {
        const float2 u0 = *(const float2*)&red[t][0][lc];
        const float2 u1 = *(const float2*)&red[t][1][lc];
        const float2 u2 = *(const float2*)&red[t][2][lc];
        const float2 u3 = *(const float2*)&red[t][3][lc];
        c[t].x = (u0.x + u1.x) + (u2.x + u3.x);
        c[t].y = (u0.y + u1.y) + (u2.y + u3.y);
    }

    // --- tiny triangular solve for d_t (per lane, its 2 cols) ---
    float2 d0, d1, d2, d3;
    d0.x = bt0 * (va[0].x - G0 * c[0].x);
    d0.y = bt0 * (va[0].y - G0 * c[0].y);
    d1.x = bt1 * (va[1].x - G1 * c[1].x - M01 * AA[0][1] * d0.x);
    d1.y = bt1 * (va[1].y - G1 * c[1].y - M01 * AA[0][1] * d0.y);
    d2.x = bt2 * (va[2].x - G2 * c[2].x - M02 * AA[0][2] * d0.x - M12 * AA[1][2] * d1.x);
    d2.y = bt2 * (va[2].y - G2 * c[2].y - M02 * AA[0][2] * d0.y - M12 * AA[1][2] * d1.y);
    d3.x = bt3 * (va[3].x - G3 * c[3].x - M03 * AA[0][3] * d0.x - M13 * AA[1][3] * d1.x - M23 * AA[2][3] * d2.x);
    d3.y = bt3 * (va[3].y - G3 * c[3].y - M03 * AA[0][3] * d0.y - M13 * AA[1][3] * d1.y - M23 * AA[2][3] * d2.y);

    // --- pass 2: p_t partials + fused state update + immediate store ---
    const float W0t = M03, W1t = M13, W2t = M23;   // W3 = 1
    float2 p[TT] = {{0.f,0.f},{0.f,0.f},{0.f,0.f},{0.f,0.f}};
#pragma unroll
    for (int i = 0; i < RPW; ++i) {
        const int r = r0 + i;
        const float4 k4 = *(const float4*)&ksh[r][0];   // broadcast
        const float4 q4 = *(const float4*)&qsh[r][0];   // broadcast
        const float2 s = s2[i];
        p[0].x = fmaf(s.x, q4.x, p[0].x); p[0].y = fmaf(s.y, q4.x, p[0].y);
        p[1].x = fmaf(s.x, q4.y, p[1].x); p[1].y = fmaf(s.y, q4.y, p[1].y);
        p[2].x = fmaf(s.x, q4.z, p[2].x); p[2].y = fmaf(s.y, q4.z, p[2].y);
        p[3].x = fmaf(s.x, q4.w, p[3].x); p[3].y = fmaf(s.y, q4.w, p[3].y);
        const float h0 = W0t * k4.x, h1 = W1t * k4.y, h2 = W2t * k4.z, h3 = k4.w;
        float nx = s.x * E, ny = s.y * E;
        nx = fmaf(h0, d0.x, nx); ny = fmaf(h0, d0.y, ny);
        nx = fmaf(h1, d1.x, nx); ny = fmaf(h1, d1.y, ny);
        nx = fmaf(h2, d2.x, nx); ny = fmaf(h2, d2.y, ny);
        nx = fmaf(h3, d3.x, nx); ny = fmaf(h3, d3.y, ny);
        *(float2*)&sout_p[(size_t)r * DV + col] = make_float2(nx, ny);
    }

    __syncthreads();                      // barrier 3: all c-reads of red done
#pragma unroll
    for (int t = 0; t < TT; ++t)
        *(float2*)&red[t][w][lc] = p[t];
    __syncthreads();                      // barrier 4: p partials visible

    // --- o_t = G[t] p_t + sum_{s<=t} M[s][t] B[s][t] d_s; wave w stores t=w ---
    const float2 darr[4] = {d0, d1, d2, d3};
    const float Gt[4] = {G0, G1, G2, G3};
    const float Mm[4][4] = {{1.f, M01, M02, M03},
                            {0.f, 1.f, M12, M13},
                            {0.f, 0.f, 1.f, M23},
                            {0.f, 0.f, 0.f, 1.f}};
#pragma unroll
    for (int t = 0; t < TT; ++t) {
        if (w == t) {
            const float2 u0 = *(const float2*)&red[t][0][lc];
            const float2 u1 = *(const float2*)&red[t][1][lc];
            const float2 u2 = *(const float2*)&red[t][2][lc];
            const float2 u3 = *(const float2*)&red[t][3][lc];
            float ox = Gt[t] * ((u0.x + u1.x) + (u2.x + u3.x));
            float oy = Gt[t] * ((u0.y + u1.y) + (u2.y + u3.y));
#pragma unroll
            for (int s = 0; s < TT; ++s) {
                if (s <= t) {
                    const float cf = Mm[s][t] * BB[s][t];
                    ox = fmaf(cf, darr[s].x, ox);
                    oy = fmaf(cf, darr[s].y, oy);
                }
            }
            *(float2*)&out_p[t * DV + col] = make_float2(ox, oy);
        }
    }
}

extern "C" void kernel_launch(void* const* d_in, const int* in_sizes, int n_in,
                              void* d_out, int out_size, void* d_ws, size_t ws_size,
                              hipStream_t stream) {
    const float* q    = (const float*)d_in[0];
    const float* k    = (const float*)d_in[1];
    const float* v    = (const float*)d_in[2];
    const float* g    = (const float*)d_in[3];
    const float* beta = (const float*)d_in[4];
    const float* s0   = (const float*)d_in[5];
    float* out = (float*)d_out;

    delta_rule_kernel<<<dim3(BH * 2), dim3(256), 0, stream>>>(q, k, v, g, beta, s0, out);
}